// Round 7
// baseline (350.359 us; speedup 1.0000x reference)
//
#include <hip/hip_runtime.h>
#include <cstddef>

typedef __attribute__((ext_vector_type(8))) short short8;
typedef __attribute__((ext_vector_type(4))) float f32x4;

constexpr int CL = 32;    // scan chunk length
constexpr int NB = 256;   // grid blocks == CU count -> co-residency guaranteed

__device__ inline ushort tobf(float f) {
  union { float f; unsigned u; } v; v.f = f;
  return (ushort)((v.u + 0x7FFFu + ((v.u >> 16) & 1u)) >> 16);
}
__device__ inline float frombf(ushort u) {
  union { unsigned u; float f; } v; v.u = ((unsigned)u) << 16; return v.f;
}

// ---- grid barrier: per-phase monotonic counter, init'd by bar_init ---------
__global__ void bar_init(unsigned* cnt) {
  if (threadIdx.x < 16) cnt[threadIdx.x] = 0;
}

__device__ __forceinline__ void gbar(unsigned* cnt, int phase) {
  __syncthreads();
  if (threadIdx.x == 0) {
    __threadfence();                         // release (agent scope: L2 wb)
    atomicAdd(&cnt[phase], 1u);              // device-scope by default [m20]
    while (__hip_atomic_load(&cnt[phase], __ATOMIC_RELAXED,
                             __HIP_MEMORY_SCOPE_AGENT) < (unsigned)NB)
      __builtin_amdgcn_s_sleep(2);
    __threadfence();                         // acquire (buffer_inv)
  }
  __syncthreads();
}

// ---- bf16 MFMA GEMM phase: A[M][K], BT[N][K], 64x64 tile -------------------
// MODE 0: Cbf[gm*N+gn] = tobf(acc + bias[gn]), full K.
// MODE 1: atomicAdd(&Cf[gm*N+gn], acc), K-slice bz*kchunk.
// XOR-swizzle applied to FULL byte offset both sides (rule #21).
template<int MODE>
__device__ __forceinline__ void gemm_phase(
    int vb, int nxt, int kchunk,
    const ushort* __restrict__ Ab, const ushort* __restrict__ BT,
    const float* __restrict__ bias, float* __restrict__ Cf,
    ushort* __restrict__ Cbf, int M, int N, int K, char* SMEM) {
  ushort* sA = (ushort*)SMEM;
  ushort* sB = (ushort*)(SMEM + 16384);
  const int t = threadIdx.x;
  const int bx = vb % nxt;
  const int rest = vb / nxt;
  const int by = rest & 31;                  // 32 m-tiles always
  const int bz = rest >> 5;
  const int n0 = bx * 64, m0 = by * 64;
  const int k0 = (MODE == 1) ? bz * kchunk : 0;
  const int k1 = (MODE == 1) ? k0 + kchunk : K;

  const int lane = t & 63, w = t >> 6;
  const int wr = w << 4;
  const int colsel = lane & 15;
  const int kg = lane >> 4;

  f32x4 acc[4];
  #pragma unroll
  for (int nf = 0; nf < 4; ++nf) acc[nf] = (f32x4)(0.f);

  for (int kc = k0; kc < k1; kc += 128) {
    __syncthreads();
    #pragma unroll
    for (int i = 0; i < 4; ++i) {
      int c = t + (i << 8);
      int row = c >> 4, kk = (c & 15) << 3;
      float4 va  = *(const float4*)(Ab + (size_t)(m0 + row) * K + kc + kk);
      float4 vb4 = *(const float4*)(BT + (size_t)(n0 + row) * K + kc + kk);
      int byteoff = ((row << 8) + (kk << 1)) ^ ((row & 7) << 4);
      *(float4*)((char*)sA + byteoff) = va;
      *(float4*)((char*)sB + byteoff) = vb4;
    }
    __syncthreads();
    short8 a[4];
    {
      int arow = wr + colsel;
      int lin = (arow << 8) + (kg << 4);
      int swz = (arow & 7) << 4;
      #pragma unroll
      for (int ks = 0; ks < 4; ++ks)
        a[ks] = *(const short8*)((const char*)sA + ((lin + (ks << 6)) ^ swz));
    }
    #pragma unroll
    for (int nf = 0; nf < 4; ++nf) {
      int brow = (nf << 4) + colsel;
      int lin = (brow << 8) + (kg << 4);
      int swz = (brow & 7) << 4;
      #pragma unroll
      for (int ks = 0; ks < 4; ++ks) {
        short8 b = *(const short8*)((const char*)sB + ((lin + (ks << 6)) ^ swz));
        acc[nf] = __builtin_amdgcn_mfma_f32_16x16x32_bf16(a[ks], b, acc[nf], 0, 0, 0);
      }
    }
  }
  // D layout: col=lane&15, row=(lane>>4)*4+reg  [m89]
  const int r4 = kg << 2;
  #pragma unroll
  for (int nf = 0; nf < 4; ++nf) {
    int gn = n0 + (nf << 4) + colsel;
    #pragma unroll
    for (int reg = 0; reg < 4; ++reg) {
      int gm = m0 + wr + r4 + reg;
      if (MODE == 0) {
        Cbf[(size_t)gm * N + gn] = tobf(acc[nf][reg] + bias[gn]);
      } else {
        atomicAdd(&Cf[(size_t)gm * N + gn], acc[nf][reg]);
      }
    }
  }
}

// ============================================================================
// Mega-kernel: 9 phases, 8 manual grid barriers. 256 blocks x 256 threads.
// ============================================================================
__global__ __launch_bounds__(256) void mamba_mega(
    const float* __restrict__ x, const float* __restrict__ Wemb,
    const float* __restrict__ bemb, const float* __restrict__ Wxp,
    const float* __restrict__ bxp, const float* __restrict__ A,
    const float* __restrict__ Dp, const float* __restrict__ gamma,
    const float* __restrict__ beta, const float* __restrict__ Wout,
    const float* __restrict__ bout, float* __restrict__ out,
    float* __restrict__ ws) {
  const int bid = blockIdx.x;
  const int t = threadIdx.x, lane = t & 63, w = t >> 6;
  __shared__ __align__(16) char SMEM[32768];

  // ws layout (floats)
  float* sel = ws;                        //   393,216 (bias-init, G2 atomics)
  float* abc = ws + 393216;               //   393,216
  float* cst = ws + 786432;               // 3,932,160
  float* y   = ws + 4718592;              // 2,097,152
  float* Ach = ws + 6815744;              //     4,096
  unsigned* cnt = (unsigned*)(ws + 6819840);   // 16
  ushort* ubf   = (ushort*)(ws + 6819856);     // 2,097,152 us
  ushort* ynbf  = ubf + 2097152;
  ushort* xbf   = ynbf + 2097152;         //   262,144 us
  ushort* WembT = xbf + 262144;           //   131,072 us
  ushort* wBCdT = WembT + 131072;         //   196,608 us ([192][1024], row128=wd)
  ushort* WoutT = wBCdT + 196608;         //   131,072 us

  // ---- P0: prep — transposes to bf16 [N][K] + x cast ----------------------
  for (int vb = bid; vb < 2816; vb += NB) {
    int idx = vb * 256 + t;
    if (idx < 131072) {                       // WembT[n][k] <- Wemb[k][n]
      int k = idx >> 10, n = idx & 1023;
      WembT[n * 128 + k] = tobf(Wemb[idx]);
    } else if (idx < 263168) {                // Wxp (1024x129)
      int j = idx - 131072;
      int k = j / 129, c = j - k * 129;
      ushort v2 = tobf(Wxp[j]);
      if (c == 0) wBCdT[128 * 1024 + k] = v2;
      else        wBCdT[(c - 1) * 1024 + k] = v2;
    } else if (idx < 327680) {                // zero rows 129..191
      int j = idx - 263168;
      wBCdT[129 * 1024 + j] = 0;
    } else if (idx < 458752) {                // WoutT[n][k] <- Wout[k][n]
      int j = idx - 327680;
      WoutT[(j & 127) * 1024 + (j >> 7)] = tobf(Wout[j]);
    } else if (idx < 720896) {                // x -> bf16
      int j = idx - 458752;
      xbf[j] = tobf(x[j]);
    }
  }
  gbar(cnt, 0);

  // ---- P1: G1  ubf = bf16(x @ Wemb + bemb); also sel <- bias --------------
  for (int i = bid * 256 + t; i < 393216; i += NB * 256) {
    int c = i % 192;
    sel[i] = (c < 128) ? bxp[1 + c] : (c == 128 ? bxp[0] : 0.f);
  }
  for (int vb = bid; vb < 512; vb += NB)
    gemm_phase<0>(vb, 16, 0, xbf, WembT, bemb, nullptr, ubf,
                  2048, 1024, 128, SMEM);
  gbar(cnt, 1);

  // ---- P2: G2  sel += ubf @ wBCdT^T (split-K=4 via atomics) ---------------
  for (int vb = bid; vb < 384; vb += NB)
    gemm_phase<1>(vb, 3, 256, ubf, wBCdT, nullptr, sel, nullptr,
                  2048, 192, 1024, SMEM);
  gbar(cnt, 2);

  // ---- P3: transform sel -> abc (softplus/exp) ----------------------------
  for (int vb = bid; vb < 512; vb += NB) {
    int gid = vb * 256 + t;
    int row = gid >> 6, d = gid & 63;
    const float* s = sel + (size_t)row * 192;
    float sb = s[d], sc = s[64 + d], xv = s[128];
    float sp = (xv > 15.f) ? xv : log1pf(__expf(xv));
    float delta = 0.01f * sp;
    float* o = abc + (size_t)row * 192;
    o[d]       = __expf(delta * A[d]);
    o[64 + d]  = delta * sb;
    o[128 + d] = sc;
  }
  gbar(cnt, 3);

  // ---- P4: scan_sum  per-chunk h-from-zero + a-products -------------------
  for (int vb = bid; vb < 240; vb += NB) {
    float* sbuf = (float*)SMEM;
    const int tc = vb % 15;
    const int mg = (vb / 15) & 3;
    const int b = vb / 60;
    const int r0 = b * 512 + tc * CL;
    __syncthreads();
    const float4* src = (const float4*)(abc + (size_t)r0 * 192);
    #pragma unroll
    for (int i = 0; i < 6; ++i)
      ((float4*)sbuf)[t + i * 256] = src[t + i * 256];
    __syncthreads();
    const int m = (mg * 4 + w) * 64 + lane;
    const ushort* ub = ubf + (size_t)r0 * 1024 + m;
    const bool doAp = (mg == 0 && w == 0);
    float2 h[32], ap[32];
    #pragma unroll
    for (int j = 0; j < 32; ++j) { h[j] = make_float2(0.f, 0.f); ap[j] = make_float2(1.f, 1.f); }
    float u0 = frombf(ub[0]);
    float u1 = frombf(ub[1024]);
    for (int s = 0; s < CL; ++s) {
      int sn = (s < CL - 3) ? s + 2 : CL - 1;
      float u2 = frombf(ub[(size_t)sn * 1024]);
      const float* L = sbuf + s * 192;
      #pragma unroll
      for (int jj = 0; jj < 16; ++jj) {
        float4 a4 = *(const float4*)&L[4 * jj];
        float4 b4 = *(const float4*)&L[64 + 4 * jj];
        h[2 * jj].x     = fmaf(h[2 * jj].x,     a4.x, b4.x * u0);
        h[2 * jj].y     = fmaf(h[2 * jj].y,     a4.y, b4.y * u0);
        h[2 * jj + 1].x = fmaf(h[2 * jj + 1].x, a4.z, b4.z * u0);
        h[2 * jj + 1].y = fmaf(h[2 * jj + 1].y, a4.w, b4.w * u0);
      }
      if (doAp) {
        #pragma unroll
        for (int jj = 0; jj < 16; ++jj) {
          float4 a4 = *(const float4*)&L[4 * jj];
          ap[2 * jj].x     *= a4.x;
          ap[2 * jj].y     *= a4.y;
          ap[2 * jj + 1].x *= a4.z;
          ap[2 * jj + 1].y *= a4.w;
        }
      }
      u0 = u1; u1 = u2;
    }
    size_t cbase = (((size_t)b * 15 + tc) * 64) * 1024 + m;
    #pragma unroll
    for (int j = 0; j < 32; ++j) {
      cst[cbase + (size_t)(2 * j)     * 1024] = h[j].x;
      cst[cbase + (size_t)(2 * j + 1) * 1024] = h[j].y;
    }
    if (doAp && lane == 0) {
      float2* ad = (float2*)&Ach[((size_t)b * 15 + tc) * 64];
      #pragma unroll
      for (int j = 0; j < 32; ++j) ad[j] = ap[j];
    }
  }
  gbar(cnt, 4);

  // ---- P5: chunk-state propagation ----------------------------------------
  for (int vb = bid; vb < 1024; vb += NB) {
    int g = vb * 256 + t;
    int b = g >> 16;
    int rem = g & 65535;
    int d = rem >> 10;
    int m = rem & 1023;
    float h = 0.f;
    for (int t2 = 0; t2 < 15; ++t2) {
      size_t idx = (((size_t)(b * 15 + t2)) * 64 + d) * 1024 + m;
      h = fmaf(Ach[(b * 15 + t2) * 64 + d], h, cst[idx]);
      cst[idx] = h;
    }
  }
  gbar(cnt, 5);

  // ---- P6: scan_out  replay from true init, emit y ------------------------
  for (int vb = bid; vb < 256; vb += NB) {
    float* sbuf = (float*)SMEM;
    const int tc = vb & 15;
    const int mg = (vb >> 4) & 3;
    const int b = vb >> 6;
    const int r0 = b * 512 + tc * CL;
    __syncthreads();
    const float4* src = (const float4*)(abc + (size_t)r0 * 192);
    #pragma unroll
    for (int i = 0; i < 6; ++i)
      ((float4*)sbuf)[t + i * 256] = src[t + i * 256];
    __syncthreads();
    const int m = (mg * 4 + w) * 64 + lane;
    const ushort* ub = ubf + (size_t)r0 * 1024 + m;
    float* yb = y + (size_t)r0 * 1024 + m;
    const float dp = Dp[m];
    float2 h[32];
    if (tc == 0) {
      #pragma unroll
      for (int j = 0; j < 32; ++j) h[j] = make_float2(0.f, 0.f);
    } else {
      size_t cbase = (((size_t)b * 15 + (tc - 1)) * 64) * 1024 + m;
      #pragma unroll
      for (int j = 0; j < 32; ++j) {
        h[j].x = cst[cbase + (size_t)(2 * j)     * 1024];
        h[j].y = cst[cbase + (size_t)(2 * j + 1) * 1024];
      }
    }
    float u0 = frombf(ub[0]);
    float u1 = frombf(ub[1024]);
    for (int s = 0; s < CL; ++s) {
      int sn = (s < CL - 3) ? s + 2 : CL - 1;
      float u2 = frombf(ub[(size_t)sn * 1024]);
      const float* L = sbuf + s * 192;
      float y0 = 0.f, y1 = 0.f, y2 = 0.f, y3 = 0.f;
      #pragma unroll
      for (int jj = 0; jj < 16; ++jj) {
        float4 a4 = *(const float4*)&L[4 * jj];
        float4 b4 = *(const float4*)&L[64 + 4 * jj];
        float4 c4 = *(const float4*)&L[128 + 4 * jj];
        h[2 * jj].x     = fmaf(h[2 * jj].x,     a4.x, b4.x * u0);
        h[2 * jj].y     = fmaf(h[2 * jj].y,     a4.y, b4.y * u0);
        h[2 * jj + 1].x = fmaf(h[2 * jj + 1].x, a4.z, b4.z * u0);
        h[2 * jj + 1].y = fmaf(h[2 * jj + 1].y, a4.w, b4.w * u0);
        y0 = fmaf(c4.x, h[2 * jj].x,     y0);
        y1 = fmaf(c4.y, h[2 * jj].y,     y1);
        y2 = fmaf(c4.z, h[2 * jj + 1].x, y2);
        y3 = fmaf(c4.w, h[2 * jj + 1].y, y3);
      }
      yb[(size_t)s * 1024] = (y0 + y1) + (y2 + y3) + u0 * dp;
      u0 = u1; u1 = u2;
    }
  }
  gbar(cnt, 6);

  // ---- P7: LayerNorm -> ynbf; also out <- bout ----------------------------
  for (int i = bid * 256 + t; i < 262144; i += NB * 256)
    out[i] = bout[i & 127];
  for (int vb = bid; vb < 2048; vb += NB) {
    float* red = (float*)SMEM;
    int row = vb;
    float4 v = *(const float4*)&y[(size_t)row * 1024 + t * 4];
    float s1 = v.x + v.y + v.z + v.w;
    float s2 = v.x * v.x + v.y * v.y + v.z * v.z + v.w * v.w;
    #pragma unroll
    for (int o = 32; o; o >>= 1) {
      s1 += __shfl_xor(s1, o, 64);
      s2 += __shfl_xor(s2, o, 64);
    }
    __syncthreads();
    if (lane == 0) { red[w] = s1; red[4 + w] = s2; }
    __syncthreads();
    float S1 = red[0] + red[1] + red[2] + red[3];
    float S2 = red[4] + red[5] + red[6] + red[7];
    float mean = S1 * (1.f / 1024.f);
    float var  = S2 * (1.f / 1024.f) - mean * mean;
    float rstd = rsqrtf(var + 1e-5f);
    float4 g  = *(const float4*)&gamma[t * 4];
    float4 be = *(const float4*)&beta[t * 4];
    ushort4 o4;
    o4.x = tobf((v.x - mean) * rstd * g.x + be.x);
    o4.y = tobf((v.y - mean) * rstd * g.y + be.y);
    o4.z = tobf((v.z - mean) * rstd * g.z + be.z);
    o4.w = tobf((v.w - mean) * rstd * g.w + be.w);
    *(ushort4*)&ynbf[(size_t)row * 1024 + t * 4] = o4;
  }
  gbar(cnt, 7);

  // ---- P8: G4  out += ynbf @ WoutT^T (split-K=4 via atomics) --------------
  for (int vb = bid; vb < 256; vb += NB)
    gemm_phase<1>(vb, 2, 256, ynbf, WoutT, nullptr, out, nullptr,
                  2048, 128, 1024, SMEM);
}

extern "C" void kernel_launch(void* const* d_in, const int* in_sizes, int n_in,
                              void* d_out, int out_size, void* d_ws, size_t ws_size,
                              hipStream_t stream) {
  const float* x     = (const float*)d_in[0];
  const float* Wemb  = (const float*)d_in[1];
  const float* bemb  = (const float*)d_in[2];
  const float* Wxp   = (const float*)d_in[3];
  const float* bxp   = (const float*)d_in[4];
  const float* A     = (const float*)d_in[5];
  const float* Dp    = (const float*)d_in[6];
  const float* gamma = (const float*)d_in[7];
  const float* beta  = (const float*)d_in[8];
  const float* Wout  = (const float*)d_in[9];
  const float* bout  = (const float*)d_in[10];
  float* out = (float*)d_out;
  float* ws  = (float*)d_ws;

  bar_init<<<1, 64, 0, stream>>>((unsigned*)(ws + 6819840));
  mamba_mega<<<NB, 256, 0, stream>>>(x, Wemb, bemb, Wxp, bxp, A, Dp,
                                     gamma, beta, Wout, bout, out, ws);
}

// Round 8
// 160.812 us; speedup vs baseline: 2.1787x; 2.1787x over previous
//
#include <hip/hip_runtime.h>
#include <cstddef>

typedef __attribute__((ext_vector_type(8))) short short8;
typedef __attribute__((ext_vector_type(4))) float f32x4;

constexpr int CL = 32;    // scan chunk length

__device__ inline ushort tobf(float f) {
  union { float f; unsigned u; } v; v.f = f;
  return (ushort)((v.u + 0x7FFFu + ((v.u >> 16) & 1u)) >> 16);
}
__device__ inline float frombf(ushort u) {
  union { unsigned u; float f; } v; v.u = ((unsigned)u) << 16; return v.f;
}

// ---------------- prep: bf16 weight transposes (write-coalesced), x cast,
//                  sel <- bias pre-init (for G2's atomic split-K) ------------
__global__ __launch_bounds__(256)
void prep(const float* __restrict__ Wemb, const float* __restrict__ Wxp,
          const float* __restrict__ Wout, const float* __restrict__ x,
          const float* __restrict__ bxp,
          ushort* __restrict__ WembT, ushort* __restrict__ wBCdT,
          ushort* __restrict__ WoutT, ushort* __restrict__ xbf,
          float* __restrict__ sel) {
  int idx = blockIdx.x * 256 + threadIdx.x;
  if (idx < 131072) {                        // WembT[n][k] = Wemb[k][n], K=128
    int n = idx >> 7, k = idx & 127;
    WembT[idx] = tobf(Wemb[k * 1024 + n]);
  } else if (idx < 327680) {                 // wBCdT[n][k]; n<128 BC, 128 wd, else 0
    int j = idx - 131072;
    int n = j >> 10, k = j & 1023;
    float v = (n < 128) ? Wxp[k * 129 + 1 + n] : (n == 128 ? Wxp[k * 129] : 0.f);
    wBCdT[j] = tobf(v);
  } else if (idx < 458752) {                 // WoutT[n][k] = Wout[k][n], K=1024
    int j = idx - 327680;
    int n = j >> 10, k = j & 1023;
    WoutT[j] = tobf(Wout[k * 128 + n]);
  } else if (idx < 720896) {                 // x -> bf16
    int j = idx - 458752;
    xbf[j] = tobf(x[j]);
  } else if (idx < 1114112) {                // sel <- bias (rows of 192)
    int j = idx - 720896;
    int c = j % 192;
    sel[j] = (c < 128) ? bxp[1 + c] : (c == 128 ? bxp[0] : 0.f);
  }
}

// ---------------- bf16 MFMA GEMM: A[M][K], BT[N][K], 64x64 tile -------------
// MODE 0: Cbf = tobf(acc + bias[gn]), full K.     (G1)
// MODE 1: atomicAdd(&Cf[...], acc), K-slice blockIdx.z. (G2/G4 split-K)
// XOR-swizzle applied to FULL final byte offset on both sides (rule #21).
template<int MODE>
__global__ __launch_bounds__(256)
void gemm_bt(const ushort* __restrict__ A, const ushort* __restrict__ BT,
             const float* __restrict__ bias, float* __restrict__ Cf,
             ushort* __restrict__ Cbf, int M, int N, int K, int kchunk) {
  __shared__ __align__(16) ushort sA[8192];   // [64 rows][128 k] swizzled
  __shared__ __align__(16) ushort sB[8192];
  const int t  = threadIdx.x;
  const int n0 = blockIdx.x * 64;
  const int m0 = blockIdx.y * 64;
  const int k0 = (MODE == 1) ? blockIdx.z * kchunk : 0;
  const int k1 = (MODE == 1) ? k0 + kchunk : K;

  const int lane = t & 63, w = t >> 6;
  const int wr = w << 4;
  const int colsel = lane & 15;
  const int kg = lane >> 4;

  f32x4 acc[4];
  #pragma unroll
  for (int nf = 0; nf < 4; ++nf) acc[nf] = (f32x4)(0.f);

  for (int kc = k0; kc < k1; kc += 128) {
    __syncthreads();
    #pragma unroll
    for (int i = 0; i < 4; ++i) {
      int c = t + (i << 8);
      int row = c >> 4, kk = (c & 15) << 3;
      float4 va  = *(const float4*)(A  + (size_t)(m0 + row) * K + kc + kk);
      float4 vb4 = *(const float4*)(BT + (size_t)(n0 + row) * K + kc + kk);
      int byteoff = ((row << 8) + (kk << 1)) ^ ((row & 7) << 4);
      *(float4*)((char*)sA + byteoff) = va;
      *(float4*)((char*)sB + byteoff) = vb4;
    }
    __syncthreads();
    short8 a[4];
    {
      int arow = wr + colsel;
      int lin = (arow << 8) + (kg << 4);
      int swz = (arow & 7) << 4;
      #pragma unroll
      for (int ks = 0; ks < 4; ++ks)
        a[ks] = *(const short8*)((const char*)sA + ((lin + (ks << 6)) ^ swz));
    }
    #pragma unroll
    for (int nf = 0; nf < 4; ++nf) {
      int brow = (nf << 4) + colsel;
      int lin = (brow << 8) + (kg << 4);
      int swz = (brow & 7) << 4;
      #pragma unroll
      for (int ks = 0; ks < 4; ++ks) {
        short8 b = *(const short8*)((const char*)sB + ((lin + (ks << 6)) ^ swz));
        acc[nf] = __builtin_amdgcn_mfma_f32_16x16x32_bf16(a[ks], b, acc[nf], 0, 0, 0);
      }
    }
  }
  // D layout: col=lane&15, row=(lane>>4)*4+reg  [m89]
  const int r4 = kg << 2;
  #pragma unroll
  for (int nf = 0; nf < 4; ++nf) {
    int gn = n0 + (nf << 4) + colsel;
    #pragma unroll
    for (int reg = 0; reg < 4; ++reg) {
      int gm = m0 + wr + r4 + reg;
      if (MODE == 0) {
        Cbf[(size_t)gm * N + gn] = tobf(acc[nf][reg] + bias[gn]);
      } else {
        atomicAdd(&Cf[(size_t)gm * N + gn], acc[nf][reg]);
      }
    }
  }
}

// ---- in-LDS sel->abc transform. sbuf rows [32][192]: on entry [0:64]=B+bias,
// [64:128]=C, [128]=draw. On exit: [0:64]=B_bar, [64:128]=C, [128:192]=A_bar.
// One wave owns each row per iteration -> wave-synchronous, no extra sync.
__device__ __forceinline__ void transform_sbuf(float* sbuf, float a_d, int t) {
  const int d = t & 63;
  #pragma unroll
  for (int i = 0; i < 8; ++i) {
    float* R = sbuf + ((t >> 6) + i * 4) * 192;
    float draw = R[128];
    float sp = (draw > 15.f) ? draw : log1pf(__expf(draw));
    float delta = 0.01f * sp;
    R[d] = delta * R[d];
    R[128 + d] = __expf(delta * a_d);
  }
}

// ============================================================================
// Chunked scan (3 phases). lane = m, all 64 d in registers.
// sbuf layout after transform: B_bar=[0:64], C=[64:128], A_bar=[128:192].
// ============================================================================
__global__ __launch_bounds__(256)
void scan_sum(const ushort* __restrict__ ubf, const float* __restrict__ sel,
              const float* __restrict__ A,
              float* __restrict__ cst, float* __restrict__ Ach) {
  __shared__ __align__(16) float sbuf[CL * 192];
  const int t = threadIdx.x, lane = t & 63, w = t >> 6;
  const int tc = blockIdx.x % 15;
  const int mg = (blockIdx.x / 15) & 3;
  const int b  = blockIdx.x / 60;
  const int r0 = b * 512 + tc * CL;

  const float a_d = A[t & 63];
  const float4* src = (const float4*)(sel + (size_t)r0 * 192);
  #pragma unroll
  for (int i = 0; i < 6; ++i)
    ((float4*)sbuf)[t + i * 256] = src[t + i * 256];
  __syncthreads();
  transform_sbuf(sbuf, a_d, t);
  __syncthreads();

  const int m = (mg * 4 + w) * 64 + lane;
  const ushort* ub = ubf + (size_t)r0 * 1024 + m;
  const bool doAp = (mg == 0 && w == 0);

  float2 h[32], ap[32];
  #pragma unroll
  for (int j = 0; j < 32; ++j) { h[j] = make_float2(0.f, 0.f); ap[j] = make_float2(1.f, 1.f); }

  float u0 = frombf(ub[0]);
  float u1 = frombf(ub[1024]);
  for (int s = 0; s < CL; ++s) {
    int sn = (s < CL - 3) ? s + 2 : CL - 1;
    float u2 = frombf(ub[(size_t)sn * 1024]);
    const float* L = sbuf + s * 192;
    #pragma unroll
    for (int jj = 0; jj < 16; ++jj) {
      float4 a4 = *(const float4*)&L[128 + 4 * jj];
      float4 b4 = *(const float4*)&L[4 * jj];
      h[2 * jj].x     = fmaf(h[2 * jj].x,     a4.x, b4.x * u0);
      h[2 * jj].y     = fmaf(h[2 * jj].y,     a4.y, b4.y * u0);
      h[2 * jj + 1].x = fmaf(h[2 * jj + 1].x, a4.z, b4.z * u0);
      h[2 * jj + 1].y = fmaf(h[2 * jj + 1].y, a4.w, b4.w * u0);
    }
    if (doAp) {
      #pragma unroll
      for (int jj = 0; jj < 16; ++jj) {
        float4 a4 = *(const float4*)&L[128 + 4 * jj];
        ap[2 * jj].x     *= a4.x;
        ap[2 * jj].y     *= a4.y;
        ap[2 * jj + 1].x *= a4.z;
        ap[2 * jj + 1].y *= a4.w;
      }
    }
    u0 = u1; u1 = u2;
  }

  size_t cbase = (((size_t)b * 15 + tc) * 64) * 1024 + m;
  #pragma unroll
  for (int j = 0; j < 32; ++j) {
    cst[cbase + (size_t)(2 * j)     * 1024] = h[j].x;
    cst[cbase + (size_t)(2 * j + 1) * 1024] = h[j].y;
  }
  if (doAp && lane == 0) {
    float2* ad = (float2*)&Ach[((size_t)b * 15 + tc) * 64];
    #pragma unroll
    for (int j = 0; j < 32; ++j) ad[j] = ap[j];
  }
}

__global__ __launch_bounds__(256)
void scan_comb(float* __restrict__ cst, const float* __restrict__ Ach) {
  int g = blockIdx.x * 256 + threadIdx.x;  // 0..262143
  int b = g >> 16;
  int rem = g & 65535;
  int d = rem >> 10;
  int m = rem & 1023;
  float h = 0.f;
  for (int t2 = 0; t2 < 15; ++t2) {
    size_t idx = (((size_t)(b * 15 + t2)) * 64 + d) * 1024 + m;
    h = fmaf(Ach[(b * 15 + t2) * 64 + d], h, cst[idx]);
    cst[idx] = h;
  }
}

__global__ __launch_bounds__(256)
void scan_out(const ushort* __restrict__ ubf, const float* __restrict__ sel,
              const float* __restrict__ A, const float* __restrict__ cst,
              const float* __restrict__ Dp, float* __restrict__ y) {
  __shared__ __align__(16) float sbuf[CL * 192];
  const int t = threadIdx.x, lane = t & 63, w = t >> 6;
  const int tc = blockIdx.x & 15;
  const int mg = (blockIdx.x >> 4) & 3;
  const int b  = blockIdx.x >> 6;
  const int r0 = b * 512 + tc * CL;

  const float a_d = A[t & 63];
  const float4* src = (const float4*)(sel + (size_t)r0 * 192);
  #pragma unroll
  for (int i = 0; i < 6; ++i)
    ((float4*)sbuf)[t + i * 256] = src[t + i * 256];
  __syncthreads();
  transform_sbuf(sbuf, a_d, t);
  __syncthreads();

  const int m = (mg * 4 + w) * 64 + lane;
  const ushort* ub = ubf + (size_t)r0 * 1024 + m;
  float* yb = y + (size_t)r0 * 1024 + m;
  const float dp = Dp[m];

  float2 h[32];
  if (tc == 0) {
    #pragma unroll
    for (int j = 0; j < 32; ++j) h[j] = make_float2(0.f, 0.f);
  } else {
    size_t cbase = (((size_t)b * 15 + (tc - 1)) * 64) * 1024 + m;
    #pragma unroll
    for (int j = 0; j < 32; ++j) {
      h[j].x = cst[cbase + (size_t)(2 * j)     * 1024];
      h[j].y = cst[cbase + (size_t)(2 * j + 1) * 1024];
    }
  }

  float u0 = frombf(ub[0]);
  float u1 = frombf(ub[1024]);
  for (int s = 0; s < CL; ++s) {
    int sn = (s < CL - 3) ? s + 2 : CL - 1;
    float u2 = frombf(ub[(size_t)sn * 1024]);
    const float* L = sbuf + s * 192;
    float y0 = 0.f, y1 = 0.f, y2 = 0.f, y3 = 0.f;
    #pragma unroll
    for (int jj = 0; jj < 16; ++jj) {
      float4 a4 = *(const float4*)&L[128 + 4 * jj];
      float4 b4 = *(const float4*)&L[4 * jj];
      float4 c4 = *(const float4*)&L[64 + 4 * jj];
      h[2 * jj].x     = fmaf(h[2 * jj].x,     a4.x, b4.x * u0);
      h[2 * jj].y     = fmaf(h[2 * jj].y,     a4.y, b4.y * u0);
      h[2 * jj + 1].x = fmaf(h[2 * jj + 1].x, a4.z, b4.z * u0);
      h[2 * jj + 1].y = fmaf(h[2 * jj + 1].y, a4.w, b4.w * u0);
      y0 = fmaf(c4.x, h[2 * jj].x,     y0);
      y1 = fmaf(c4.y, h[2 * jj].y,     y1);
      y2 = fmaf(c4.z, h[2 * jj + 1].x, y2);
      y3 = fmaf(c4.w, h[2 * jj + 1].y, y3);
    }
    yb[(size_t)s * 1024] = (y0 + y1) + (y2 + y3) + u0 * dp;
    u0 = u1; u1 = u2;
  }
}

// ---------------- LN over 1024 -> ynbf (bf16); also out <- bout init --------
__global__ __launch_bounds__(256)
void k4a_ln(const float* __restrict__ y, const float* __restrict__ gamma,
            const float* __restrict__ beta, ushort* __restrict__ ynbf,
            const float* __restrict__ bout, float* __restrict__ out) {
  __shared__ float red[8];
  int t = threadIdx.x, lane = t & 63, wv = t >> 6;
  int gi = blockIdx.x * 256 + t;
  if (gi < 262144) out[gi] = bout[gi & 127];
  int row = blockIdx.x;
  float4 v = *(const float4*)&y[(size_t)row * 1024 + t * 4];
  float s1 = v.x + v.y + v.z + v.w;
  float s2 = v.x * v.x + v.y * v.y + v.z * v.z + v.w * v.w;
  #pragma unroll
  for (int o = 32; o; o >>= 1) {
    s1 += __shfl_xor(s1, o, 64);
    s2 += __shfl_xor(s2, o, 64);
  }
  if (lane == 0) { red[wv] = s1; red[4 + wv] = s2; }
  __syncthreads();
  float S1 = red[0] + red[1] + red[2] + red[3];
  float S2 = red[4] + red[5] + red[6] + red[7];
  float mean = S1 * (1.f / 1024.f);
  float var  = S2 * (1.f / 1024.f) - mean * mean;
  float rstd = rsqrtf(var + 1e-5f);
  float4 g  = *(const float4*)&gamma[t * 4];
  float4 be = *(const float4*)&beta[t * 4];
  ushort4 o4;
  o4.x = tobf((v.x - mean) * rstd * g.x + be.x);
  o4.y = tobf((v.y - mean) * rstd * g.y + be.y);
  o4.z = tobf((v.z - mean) * rstd * g.z + be.z);
  o4.w = tobf((v.w - mean) * rstd * g.w + be.w);
  *(ushort4*)&ynbf[(size_t)row * 1024 + t * 4] = o4;
}

extern "C" void kernel_launch(void* const* d_in, const int* in_sizes, int n_in,
                              void* d_out, int out_size, void* d_ws, size_t ws_size,
                              hipStream_t stream) {
  const float* x     = (const float*)d_in[0];
  const float* Wemb  = (const float*)d_in[1];
  const float* bemb  = (const float*)d_in[2];
  const float* Wxp   = (const float*)d_in[3];
  const float* bxp   = (const float*)d_in[4];
  const float* A     = (const float*)d_in[5];
  const float* Dp    = (const float*)d_in[6];
  const float* gamma = (const float*)d_in[7];
  const float* beta  = (const float*)d_in[8];
  const float* Wout  = (const float*)d_in[9];
  const float* bout  = (const float*)d_in[10];
  float* out = (float*)d_out;
  float* ws  = (float*)d_ws;

  // ws layout (floats)
  float* sel = ws;                         //   393,216
  float* cst = ws + 393216;                // 3,932,160
  float* y   = ws + 4325376;               // 2,097,152
  float* Ach = ws + 6422528;               //     4,096
  ushort* ubf   = (ushort*)(ws + 6426624); // 2,097,152 us
  ushort* ynbf  = ubf + 2097152;           // 2,097,152 us
  ushort* xbf   = ynbf + 2097152;          //   262,144 us
  ushort* WembT = xbf + 262144;            //   131,072 us
  ushort* wBCdT = WembT + 131072;          //   196,608 us
  ushort* WoutT = wBCdT + 196608;          //   131,072 us

  // P0: prep (transposes + x cast + sel bias-init)
  prep<<<4352, 256, 0, stream>>>(Wemb, Wxp, Wout, x, bxp,
                                 WembT, wBCdT, WoutT, xbf, sel);
  // P1: G1  ubf = bf16(x @ Wemb + bemb)
  gemm_bt<0><<<dim3(16, 32, 1), 256, 0, stream>>>(
      xbf, WembT, bemb, nullptr, ubf, 2048, 1024, 128, 0);
  // P2: G2  sel += ubf @ wBCdT^T  (split-K=4, atomics)
  gemm_bt<1><<<dim3(3, 32, 4), 256, 0, stream>>>(
      ubf, wBCdT, nullptr, sel, nullptr, 2048, 192, 1024, 256);
  // P3-P5: chunked scan (transform inlined in sum/out)
  scan_sum<<<240, 256, 0, stream>>>(ubf, sel, A, cst, Ach);
  scan_comb<<<1024, 256, 0, stream>>>(cst, Ach);
  scan_out<<<256, 256, 0, stream>>>(ubf, sel, A, cst, Dp, y);
  // P6: LN -> ynbf; out <- bout
  k4a_ln<<<2048, 256, 0, stream>>>(y, gamma, beta, ynbf, bout, out);
  // P7: G4  out += ynbf @ WoutT^T  (split-K=4, atomics)
  gemm_bt<1><<<dim3(2, 32, 4), 256, 0, stream>>>(
      ynbf, WoutT, nullptr, out, nullptr, 2048, 128, 1024, 256);
}